// Round 10
// baseline (1374.905 us; speedup 1.0000x reference)
//
#include <hip/hip_runtime.h>

#define SLOPE 0.2f
#define NPB 16  // nodes per block in tiled projection kernels

typedef float vf4 __attribute__((ext_vector_type(4)));
typedef float vf2 __attribute__((ext_vector_type(2)));
typedef _Float16 vh2 __attribute__((ext_vector_type(2)));
typedef _Float16 vh8 __attribute__((ext_vector_type(8)));

__device__ __forceinline__ float bcast_lane(float v, int k) {
    return __uint_as_float(__builtin_amdgcn_readlane(__float_as_uint(v), k));
}
// sum over each 16-lane row; result valid in lane 15 of each row (row_shr DPP)
__device__ __forceinline__ float dpp_sum16(float x) {
    x += __uint_as_float(__builtin_amdgcn_update_dpp(
        0, (int)__float_as_uint(x), 0x111, 0xf, 0xf, true));
    x += __uint_as_float(__builtin_amdgcn_update_dpp(
        0, (int)__float_as_uint(x), 0x112, 0xf, 0xf, true));
    x += __uint_as_float(__builtin_amdgcn_update_dpp(
        0, (int)__float_as_uint(x), 0x114, 0xf, 0xf, true));
    x += __uint_as_float(__builtin_amdgcn_update_dpp(
        0, (int)__float_as_uint(x), 0x118, 0xf, 0xf, true));
    return x;
}

// ============================ CSR build =====================================

__global__ __launch_bounds__(256) void k_deg(
    const int* __restrict__ dst, int* __restrict__ deg, int E)
{
    const int e = blockIdx.x * 256 + threadIdx.x;
    if (e < E) atomicAdd(&deg[dst[e]], 1);
}

__global__ __launch_bounds__(1024) void k_scan(
    const int* __restrict__ deg, int* __restrict__ offs,
    int* __restrict__ cursor, int n)
{
    __shared__ int wsum[16];
    __shared__ int carry_s;
    if (threadIdx.x == 0) carry_s = 0;
    __syncthreads();
    const int lane = threadIdx.x & 63, wid = threadIdx.x >> 6;
    for (int base = 0; base < n; base += 4096) {
        const int i0 = base + threadIdx.x * 4;
        const int d0 = (i0     < n) ? deg[i0]     : 0;
        const int d1 = (i0 + 1 < n) ? deg[i0 + 1] : 0;
        const int d2 = (i0 + 2 < n) ? deg[i0 + 2] : 0;
        const int d3 = (i0 + 3 < n) ? deg[i0 + 3] : 0;
        const int v = d0 + d1 + d2 + d3;
        int x = v;
        for (int dd = 1; dd < 64; dd <<= 1) {
            int y = __shfl_up(x, dd, 64);
            if (lane >= dd) x += y;
        }
        if (lane == 63) wsum[wid] = x;
        __syncthreads();
        if (threadIdx.x < 16) {
            int t = wsum[threadIdx.x];
            for (int dd = 1; dd < 16; dd <<= 1) {
                int y = __shfl_up(t, dd, 64);
                if ((int)threadIdx.x >= dd) t += y;
            }
            wsum[threadIdx.x] = t;
        }
        __syncthreads();
        int excl = carry_s + (wid ? wsum[wid - 1] : 0) + (x - v);
        if (i0     < n) { offs[i0]     = excl; cursor[i0]     = excl; }
        excl += d0;
        if (i0 + 1 < n) { offs[i0 + 1] = excl; cursor[i0 + 1] = excl; }
        excl += d1;
        if (i0 + 2 < n) { offs[i0 + 2] = excl; cursor[i0 + 2] = excl; }
        excl += d2;
        if (i0 + 3 < n) { offs[i0 + 3] = excl; cursor[i0 + 3] = excl; }
        __syncthreads();
        if (threadIdx.x == 0) carry_s += wsum[15];
        __syncthreads();
    }
    if (threadIdx.x == 0) offs[n] = carry_s;
}

// srcs[p] = src node of CSR slot p; pos[e] = CSR slot of edge e
__global__ __launch_bounds__(256) void k_scatter(
    const int* __restrict__ src, const int* __restrict__ dst,
    int* __restrict__ cursor, int* __restrict__ srcs, int* __restrict__ pos,
    int E)
{
    const int e = blockIdx.x * 256 + threadIdx.x;
    if (e >= E) return;
    const int p = atomicAdd(&cursor[dst[e]], 1);
    srcs[p] = src[e];
    pos[e] = p;
}

// ======= edge-feature GEMM: eproj[pos[e]] = ef[e] @ W1fij  (fp16, CSR order)
__global__ __launch_bounds__(256) void k_eproj(
    const float* __restrict__ ef, const int* __restrict__ pos,
    const float* __restrict__ Wfij, _Float16* __restrict__ ep, int E)
{
    const int e = blockIdx.x * 256 + threadIdx.x;
    if (e >= E) return;
    const vf4* __restrict__ er = (const vf4*)(ef + (size_t)e * 32);
    vf4 q[8];
#pragma unroll
    for (int i = 0; i < 8; i++) q[i] = __builtin_nontemporal_load(er + i);
    _Float16* __restrict__ op = ep + ((size_t)(unsigned)pos[e] << 6);
#pragma unroll
    for (int cc = 0; cc < 4; cc++) {
        float acc[16];
#pragma unroll
        for (int j = 0; j < 16; j++) acc[j] = 0.f;
        for (int k = 0; k < 32; k++) {
            const float ev = q[k >> 2][k & 3];
            // wave-uniform W chunk -> scalar loads
            const vf4* __restrict__ wr = (const vf4*)(Wfij + k * 64 + cc * 16);
#pragma unroll
            for (int jj = 0; jj < 4; jj++) {
                const vf4 wv = wr[jj];
                acc[jj * 4 + 0] = fmaf(ev, wv.x, acc[jj * 4 + 0]);
                acc[jj * 4 + 1] = fmaf(ev, wv.y, acc[jj * 4 + 1]);
                acc[jj * 4 + 2] = fmaf(ev, wv.z, acc[jj * 4 + 2]);
                acc[jj * 4 + 3] = fmaf(ev, wv.w, acc[jj * 4 + 3]);
            }
        }
        vh8 o0, o1;
#pragma unroll
        for (int j = 0; j < 8; j++) { o0[j] = (_Float16)acc[j]; o1[j] = (_Float16)acc[8 + j]; }
        *(vh8*)(op + cc * 16)     = o0;
        *(vh8*)(op + cc * 16 + 8) = o1;
    }
}

// ======= layer-1 node projections + fp16 copy of nf =========================
__global__ __launch_bounds__(256) void k_nodeproj1(
    const float* __restrict__ nf, const float* __restrict__ Wni,
    const float* __restrict__ Wnj,
    float* __restrict__ fni, float* __restrict__ fnj,
    _Float16* __restrict__ nf16, int n)
{
    __shared__ float s[128][20];
    const int t = threadIdx.x;
    const int node0 = blockIdx.x * NPB;
    for (int i = 0; i < 8; i++) {
        const int idx = i * 256 + t;
        const int k = idx & 127, nl = idx >> 7;
        const int node = node0 + nl;
        const float v = (node < n) ? nf[(size_t)node * 128 + k] : 0.f;
        s[k][nl] = v;
        if (node < n) nf16[(size_t)node * 128 + k] = (_Float16)v;
    }
    __syncthreads();
    const int lane = t & 63;
    const int w4 = (t >> 6) * 4;
    float ai[4] = {0, 0, 0, 0}, aj[4] = {0, 0, 0, 0};
#pragma unroll 4
    for (int k = 0; k < 128; k++) {
        const float wi = Wni[(size_t)k * 64 + lane];
        const float wj = Wnj[(size_t)k * 64 + lane];
        const float4 sv = *(const float4*)&s[k][w4];
        const float sl[4] = {sv.x, sv.y, sv.z, sv.w};
#pragma unroll
        for (int nn = 0; nn < 4; nn++) {
            ai[nn] = fmaf(wi, sl[nn], ai[nn]);
            aj[nn] = fmaf(wj, sl[nn], aj[nn]);
        }
    }
#pragma unroll
    for (int nn = 0; nn < 4; nn++) {
        const int node = node0 + w4 + nn;
        if (node < n) {
            fni[(size_t)node * 64 + lane] = ai[nn];
            fnj[(size_t)node * 64 + lane] = aj[nn];
        }
    }
}

// ====== layer-1 fused: edge logits + softmax + nf-space aggregate ===========
// wave per dst node; lane = h*16 + c. Emits g2s = fe @ W2fij as well.
__global__ __launch_bounds__(256, 4) void k_l1(
    const int* __restrict__ offs, const int* __restrict__ srcs,
    const _Float16* __restrict__ ep, const _Float16* __restrict__ nf16,
    const float* __restrict__ fni, const float* __restrict__ fnj,
    const float* __restrict__ bedge, const float* __restrict__ attn,
    const float* __restrict__ Wfij2,
    float* __restrict__ g2s, _Float16* __restrict__ zbuf, int n)
{
    const int lane = threadIdx.x & 63;
    const int node = __builtin_amdgcn_readfirstlane(blockIdx.x * 4 + (threadIdx.x >> 6));
    if (node >= n) return;
    const int beg = offs[node], end = offs[node + 1];
    const float fjb = fnj[(size_t)node * 64 + lane] + bedge[lane];
    const float at = attn[lane];
    const float w2f = Wfij2[(lane & 15) * 4 + (lane >> 4)];

    float s0 = 0.f, s1 = 0.f, s2 = 0.f, s3 = 0.f;
    vf2 z0 = {0.f, 0.f}, z1 = {0.f, 0.f}, z2 = {0.f, 0.f}, z3 = {0.f, 0.f};

    for (int base = beg; base < end; base += 64) {
        const int rem = end - base;
        const int cnt = (rem < 64) ? rem : 64;
        const int idx = base + ((lane < cnt) ? lane : (cnt - 1));
        const int spv = srcs[idx];
        for (int it = 0; it < cnt; ++it) {
            const int sp = __builtin_amdgcn_readlane(spv, it);
            const int p = base + it;
            // CSR-ordered edge projection: coalesced 2B/lane
            const float epv = (float)ep[((size_t)p << 6) + lane];
            const float f = fni[(size_t)(unsigned)sp * 64 + lane] + fjb + epv;
            const float fl = (f > 0.f) ? f : SLOPE * f;
            // relu-head-mean: every lane holds 4*fe[c], c=lane&15
            float r = fmaxf(fl, 0.f);
            r += __shfl_xor(r, 16, 64);
            r += __shfl_xor(r, 32, 64);
            // g2[h] = sum_c fe[c]*W2fij[c][h] -> lane 15 of each row
            float g = dpp_sum16(0.25f * r * w2f);
            if ((lane & 15) == 15)
                g2s[(size_t)p * 4 + (lane >> 4)] = g;
            // attention logits -> exp (logits are small; no max subtraction)
            const float t = dpp_sum16(fl * at);
            const float ce = __expf(t);
            const float c0 = bcast_lane(ce, 15);
            const float c1 = bcast_lane(ce, 31);
            const float c2 = bcast_lane(ce, 47);
            const float c3 = bcast_lane(ce, 63);
            // source node raw features (fp16): channels (2*lane, 2*lane+1)
            const vh2 nvh = *(const vh2*)(nf16 + (size_t)(unsigned)sp * 128 + lane * 2);
            const float nvx = (float)nvh.x, nvy = (float)nvh.y;
            s0 += c0; s1 += c1; s2 += c2; s3 += c3;
            z0.x = fmaf(c0, nvx, z0.x); z0.y = fmaf(c0, nvy, z0.y);
            z1.x = fmaf(c1, nvx, z1.x); z1.y = fmaf(c1, nvy, z1.y);
            z2.x = fmaf(c2, nvx, z2.x); z2.y = fmaf(c2, nvy, z2.y);
            z3.x = fmaf(c3, nvx, z3.x); z3.y = fmaf(c3, nvy, z3.y);
        }
    }
    const float i0 = (s0 > 0.f) ? 1.f / s0 : 0.f;
    const float i1 = (s1 > 0.f) ? 1.f / s1 : 0.f;
    const float i2 = (s2 > 0.f) ? 1.f / s2 : 0.f;
    const float i3 = (s3 > 0.f) ? 1.f / s3 : 0.f;
    // zbuf (fp16) layout: [node][h*128 + channel], channel = 2*lane (+1)
    _Float16* zb = zbuf + (size_t)node * 512;
    vh2 o;
    o.x = (_Float16)(z0.x * i0); o.y = (_Float16)(z0.y * i0);
    *(vh2*)(zb + 0   + lane * 2) = o;
    o.x = (_Float16)(z1.x * i1); o.y = (_Float16)(z1.y * i1);
    *(vh2*)(zb + 128 + lane * 2) = o;
    o.x = (_Float16)(z2.x * i2); o.y = (_Float16)(z2.y * i2);
    *(vh2*)(zb + 256 + lane * 2) = o;
    o.x = (_Float16)(z3.x * i3); o.y = (_Float16)(z3.y * i3);
    *(vh2*)(zb + 384 + lane * 2) = o;
}

// ====== z-space -> hbuf projection: hbuf = 0.25*sum_h relu(z_h@Wnode_h + b_h)
__global__ __launch_bounds__(256) void k_zproj(
    const _Float16* __restrict__ zbuf, const int* __restrict__ offs,
    const float* __restrict__ Wnode, const float* __restrict__ bnode,
    float* __restrict__ hbuf, int n)
{
    __shared__ float s[512][20];
    const int t = threadIdx.x;
    const int node0 = blockIdx.x * NPB;
    for (int i = 0; i < 16; i++) {
        const int idx = i * 256 + t;          // 0..4095 (vh2 pairs)
        const int nl = idx >> 8, kk = (idx & 255) * 2;
        const int node = node0 + nl;
        vh2 v = {0.f, 0.f};
        if (node < n) v = *(const vh2*)(zbuf + (size_t)node * 512 + kk);
        s[kk][nl]     = (float)v.x;
        s[kk + 1][nl] = (float)v.y;
    }
    __syncthreads();
    const int lane = t & 63;
    const int w4 = (t >> 6) * 4;
    bool zf[4];
    float hb[4] = {0, 0, 0, 0};
#pragma unroll
    for (int nn = 0; nn < 4; nn++) {
        const int node = node0 + w4 + nn;
        zf[nn] = (node < n) && (offs[node] < offs[node + 1]);
    }
#pragma unroll
    for (int h = 0; h < 4; h++) {
        float acc[4];
        const float bv = bnode[h * 64 + lane];
#pragma unroll
        for (int nn = 0; nn < 4; nn++) acc[nn] = zf[nn] ? bv : 0.f;
#pragma unroll 4
        for (int k = 0; k < 128; k++) {
            const float wv = Wnode[(size_t)k * 256 + h * 64 + lane];
            const float4 sv = *(const float4*)&s[h * 128 + k][w4];
            acc[0] = fmaf(wv, sv.x, acc[0]);
            acc[1] = fmaf(wv, sv.y, acc[1]);
            acc[2] = fmaf(wv, sv.z, acc[2]);
            acc[3] = fmaf(wv, sv.w, acc[3]);
        }
#pragma unroll
        for (int nn = 0; nn < 4; nn++) hb[nn] += fmaxf(acc[nn], 0.f);
    }
#pragma unroll
    for (int nn = 0; nn < 4; nn++) {
        const int node = node0 + w4 + nn;
        if (node < n) hbuf[(size_t)node * 64 + lane] = 0.25f * hb[nn];
    }
}

// ======================= layer-2 node projections ===========================
__global__ __launch_bounds__(256) void k_nodeproj2(
    const float* __restrict__ hbuf, const float* __restrict__ Wni,
    const float* __restrict__ Wnj, const float* __restrict__ Wnode,
    const float* __restrict__ bnode,
    float* __restrict__ fni2, float* __restrict__ fnj2,
    _Float16* __restrict__ ft2h, int n)
{
    __shared__ float sh[4][64];
    const int lane = threadIdx.x & 63, w = threadIdx.x >> 6;
    const int node = blockIdx.x * 4 + w;
    const int nc = (node < n) ? node : (n - 1);
    const float v = hbuf[(size_t)nc * 64 + lane];
    sh[w][lane] = v;
    __syncthreads();
    float acc = bnode[lane];
#pragma unroll 4
    for (int k = 0; k < 64; k++) acc = fmaf(sh[w][k], Wnode[k * 64 + lane], acc);
    float pi[4], pj[4];
#pragma unroll
    for (int h = 0; h < 4; h++) { pi[h] = v * Wni[lane * 4 + h]; pj[h] = v * Wnj[lane * 4 + h]; }
#pragma unroll
    for (int mk = 1; mk < 64; mk <<= 1) {
#pragma unroll
        for (int h = 0; h < 4; h++) {
            pi[h] += __shfl_xor(pi[h], mk, 64);
            pj[h] += __shfl_xor(pj[h], mk, 64);
        }
    }
    if (node < n) {
        ft2h[(size_t)node * 64 + lane] = (_Float16)acc;
        if (lane == 0) {
            *(float4*)(fni2 + (size_t)node * 4) = make_float4(pi[0], pi[1], pi[2], pi[3]);
            *(float4*)(fnj2 + (size_t)node * 4) = make_float4(pj[0], pj[1], pj[2], pj[3]);
        }
    }
}

// ====== layer-2 fused: edge logits + softmax + message passing ==============
// wave per dst node; lane = h*16 + class.
__global__ __launch_bounds__(256) void k_l2(
    const int* __restrict__ offs, const int* __restrict__ srcs,
    const float* __restrict__ g2s, const float* __restrict__ fni2,
    const float* __restrict__ fnj2, const _Float16* __restrict__ ft2h,
    const float* __restrict__ bedge2, const float* __restrict__ attn2,
    float* __restrict__ out, int n)
{
    const int lane = threadIdx.x & 63;
    const int node = __builtin_amdgcn_readfirstlane(blockIdx.x * 4 + (threadIdx.x >> 6));
    if (node >= n) return;
    const int beg = offs[node], end = offs[node + 1];
    const int h = lane >> 4;
    const float base_ = fnj2[(size_t)node * 4 + h] + bedge2[h];
    const float at = attn2[h];
    float s = 0.f, acc = 0.f;
    for (int base = beg; base < end; base += 64) {
        const int rem = end - base;
        const int cnt = (rem < 64) ? rem : 64;
        const int idx = base + ((lane < cnt) ? lane : (cnt - 1));
        const int spv = srcs[idx];
        for (int it = 0; it < cnt; ++it) {
            const int sp = __builtin_amdgcn_readlane(spv, it);
            const int p = base + it;
            const vf4 gq = *(const vf4*)(g2s + (size_t)p * 4);
            const float4 fq = *(const float4*)(fni2 + (size_t)(unsigned)sp * 4);
            const float gh = (h == 0) ? gq.x : (h == 1) ? gq.y : (h == 2) ? gq.z : gq.w;
            const float fh = (h == 0) ? fq.x : (h == 1) ? fq.y : (h == 2) ? fq.z : fq.w;
            const float f = base_ + fh + gh;
            const float fl = (f > 0.f) ? f : SLOPE * f;
            const float c = __expf(fl * at);
            s += c;
            const float ftv = (float)ft2h[(size_t)(unsigned)sp * 64 + lane];
            acc = fmaf(c, ftv, acc);
        }
    }
    out[(size_t)node * 64 + lane] = (s > 0.f) ? acc / s : 0.f;
}

extern "C" void kernel_launch(void* const* d_in, const int* in_sizes, int n_in,
                              void* d_out, int out_size, void* d_ws, size_t ws_size,
                              hipStream_t stream)
{
    const float* nfeat  = (const float*)d_in[0];
    const float* efeat  = (const float*)d_in[1];
    const int*   src    = (const int*)d_in[2];
    const int*   dst    = (const int*)d_in[3];
    const float* W1ni   = (const float*)d_in[4];
    const float* W1fij  = (const float*)d_in[5];
    const float* W1nj   = (const float*)d_in[6];
    const float* b1e    = (const float*)d_in[7];
    const float* W1node = (const float*)d_in[8];
    const float* b1n    = (const float*)d_in[9];
    const float* attn1  = (const float*)d_in[10];
    const float* W2ni   = (const float*)d_in[11];
    const float* W2fij  = (const float*)d_in[12];
    const float* W2nj   = (const float*)d_in[13];
    const float* b2e    = (const float*)d_in[14];
    const float* W2node = (const float*)d_in[15];
    const float* b2n    = (const float*)d_in[16];
    const float* attn2  = (const float*)d_in[17];
    const int n = in_sizes[0] / 128;
    const int E = in_sizes[2];
    float* out = (float*)d_out;

    char* w = (char*)d_ws;
    auto alloc = [&](size_t bytes) {
        char* p = w; w += (bytes + 255) & ~(size_t)255; return p;
    };
    _Float16* ep   = (_Float16*)alloc((size_t)E * 64 * 2);   // CSR-ordered eproj
    _Float16* zbuf = (_Float16*)alloc((size_t)n * 512 * 2);  // reused for ft2h
    float*    g2s  = (float*)alloc((size_t)E * 4 * 4);
    float*    fni  = (float*)alloc((size_t)n * 64 * 4);      // reused as hbuf
    float*    fnj  = (float*)alloc((size_t)n * 64 * 4);
    _Float16* nf16 = (_Float16*)alloc((size_t)n * 128 * 2);
    int*      deg  = (int*)alloc((size_t)n * 4);
    int*      offs = (int*)alloc((size_t)(n + 1) * 4);
    int*      curs = (int*)alloc((size_t)n * 4);
    int*      srcs = (int*)alloc((size_t)E * 4);
    int*      pos  = (int*)alloc((size_t)E * 4);
    float*    fni2 = (float*)alloc((size_t)n * 4 * 4);
    float*    fnj2 = (float*)alloc((size_t)n * 4 * 4);
    float*    hbuf = fni;                 // fni dead after k_l1
    _Float16* ft2h = zbuf;                // zbuf dead after k_zproj

    // ---- CSR build
    hipMemsetAsync(deg, 0, (size_t)n * 4, stream);
    k_deg<<<(E + 255) / 256, 256, 0, stream>>>(dst, deg, E);
    k_scan<<<1, 1024, 0, stream>>>(deg, offs, curs, n);
    k_scatter<<<(E + 255) / 256, 256, 0, stream>>>(src, dst, curs, srcs, pos, E);

    // ---- layer 1
    k_eproj<<<(E + 255) / 256, 256, 0, stream>>>(efeat, pos, W1fij, ep, E);
    k_nodeproj1<<<(n + NPB - 1) / NPB, 256, 0, stream>>>(
        nfeat, W1ni, W1nj, fni, fnj, nf16, n);
    k_l1<<<(n + 3) / 4, 256, 0, stream>>>(offs, srcs, ep, nf16,
                                          fni, fnj, b1e, attn1, W2fij,
                                          g2s, zbuf, n);
    k_zproj<<<(n + NPB - 1) / NPB, 256, 0, stream>>>(zbuf, offs, W1node, b1n,
                                                     hbuf, n);
    // ---- layer 2
    k_nodeproj2<<<(n + 3) / 4, 256, 0, stream>>>(hbuf, W2ni, W2nj, W2node, b2n,
                                                 fni2, fnj2, ft2h, n);
    k_l2<<<(n + 3) / 4, 256, 0, stream>>>(offs, srcs, g2s, fni2, fnj2, ft2h,
                                          b2e, attn2, out, n);
}

// Round 11
// 1153.060 us; speedup vs baseline: 1.1924x; 1.1924x over previous
//
#include <hip/hip_runtime.h>

#define SLOPE 0.2f
#define NPB 16  // nodes per block in tiled projection kernels

typedef float vf4 __attribute__((ext_vector_type(4)));
typedef float vf2 __attribute__((ext_vector_type(2)));
typedef _Float16 vh2 __attribute__((ext_vector_type(2)));

__device__ __forceinline__ float bcast_lane(float v, int k) {
    return __uint_as_float(__builtin_amdgcn_readlane(__float_as_uint(v), k));
}
// sum over each 16-lane row; result valid in lane 15 of each row (row_shr DPP)
__device__ __forceinline__ float dpp_sum16(float x) {
    x += __uint_as_float(__builtin_amdgcn_update_dpp(
        0, (int)__float_as_uint(x), 0x111, 0xf, 0xf, true));
    x += __uint_as_float(__builtin_amdgcn_update_dpp(
        0, (int)__float_as_uint(x), 0x112, 0xf, 0xf, true));
    x += __uint_as_float(__builtin_amdgcn_update_dpp(
        0, (int)__float_as_uint(x), 0x114, 0xf, 0xf, true));
    x += __uint_as_float(__builtin_amdgcn_update_dpp(
        0, (int)__float_as_uint(x), 0x118, 0xf, 0xf, true));
    return x;
}

// ============================ CSR build =====================================

__global__ __launch_bounds__(256) void k_deg(
    const int* __restrict__ dst, int* __restrict__ deg, int E)
{
    const int e = blockIdx.x * 256 + threadIdx.x;
    if (e < E) atomicAdd(&deg[dst[e]], 1);
}

__global__ __launch_bounds__(1024) void k_scan(
    const int* __restrict__ deg, int* __restrict__ offs,
    int* __restrict__ cursor, int n)
{
    __shared__ int wsum[16];
    __shared__ int carry_s;
    if (threadIdx.x == 0) carry_s = 0;
    __syncthreads();
    const int lane = threadIdx.x & 63, wid = threadIdx.x >> 6;
    for (int base = 0; base < n; base += 4096) {
        const int i0 = base + threadIdx.x * 4;
        const int d0 = (i0     < n) ? deg[i0]     : 0;
        const int d1 = (i0 + 1 < n) ? deg[i0 + 1] : 0;
        const int d2 = (i0 + 2 < n) ? deg[i0 + 2] : 0;
        const int d3 = (i0 + 3 < n) ? deg[i0 + 3] : 0;
        const int v = d0 + d1 + d2 + d3;
        int x = v;
        for (int dd = 1; dd < 64; dd <<= 1) {
            int y = __shfl_up(x, dd, 64);
            if (lane >= dd) x += y;
        }
        if (lane == 63) wsum[wid] = x;
        __syncthreads();
        if (threadIdx.x < 16) {
            int t = wsum[threadIdx.x];
            for (int dd = 1; dd < 16; dd <<= 1) {
                int y = __shfl_up(t, dd, 64);
                if ((int)threadIdx.x >= dd) t += y;
            }
            wsum[threadIdx.x] = t;
        }
        __syncthreads();
        int excl = carry_s + (wid ? wsum[wid - 1] : 0) + (x - v);
        if (i0     < n) { offs[i0]     = excl; cursor[i0]     = excl; }
        excl += d0;
        if (i0 + 1 < n) { offs[i0 + 1] = excl; cursor[i0 + 1] = excl; }
        excl += d1;
        if (i0 + 2 < n) { offs[i0 + 2] = excl; cursor[i0 + 2] = excl; }
        excl += d2;
        if (i0 + 3 < n) { offs[i0 + 3] = excl; cursor[i0 + 3] = excl; }
        __syncthreads();
        if (threadIdx.x == 0) carry_s += wsum[15];
        __syncthreads();
    }
    if (threadIdx.x == 0) offs[n] = carry_s;
}

__global__ __launch_bounds__(256) void k_scatter(
    const int* __restrict__ src, const int* __restrict__ dst,
    int* __restrict__ cursor, int* __restrict__ srcs, int* __restrict__ eid,
    int E)
{
    const int e = blockIdx.x * 256 + threadIdx.x;
    if (e >= E) return;
    const int p = atomicAdd(&cursor[dst[e]], 1);
    srcs[p] = src[e];
    eid[p] = e;
}

// ======= layer-1 node projections + fp16 copy of nf =========================
__global__ __launch_bounds__(256) void k_nodeproj1(
    const float* __restrict__ nf, const float* __restrict__ Wni,
    const float* __restrict__ Wnj,
    float* __restrict__ fni, float* __restrict__ fnj,
    _Float16* __restrict__ nf16, int n)
{
    __shared__ float s[128][20];
    const int t = threadIdx.x;
    const int node0 = blockIdx.x * NPB;
    for (int i = 0; i < 8; i++) {
        const int idx = i * 256 + t;
        const int k = idx & 127, nl = idx >> 7;
        const int node = node0 + nl;
        const float v = (node < n) ? nf[(size_t)node * 128 + k] : 0.f;
        s[k][nl] = v;
        if (node < n) nf16[(size_t)node * 128 + k] = (_Float16)v;
    }
    __syncthreads();
    const int lane = t & 63;
    const int w4 = (t >> 6) * 4;
    float ai[4] = {0, 0, 0, 0}, aj[4] = {0, 0, 0, 0};
#pragma unroll 4
    for (int k = 0; k < 128; k++) {
        const float wi = Wni[(size_t)k * 64 + lane];
        const float wj = Wnj[(size_t)k * 64 + lane];
        const float4 sv = *(const float4*)&s[k][w4];
        const float sl[4] = {sv.x, sv.y, sv.z, sv.w};
#pragma unroll
        for (int nn = 0; nn < 4; nn++) {
            ai[nn] = fmaf(wi, sl[nn], ai[nn]);
            aj[nn] = fmaf(wj, sl[nn], aj[nn]);
        }
    }
#pragma unroll
    for (int nn = 0; nn < 4; nn++) {
        const int node = node0 + w4 + nn;
        if (node < n) {
            fni[(size_t)node * 64 + lane] = ai[nn];
            fnj[(size_t)node * 64 + lane] = aj[nn];
        }
    }
}

// ====== layer-1 fused: edge features + softmax + nf-space aggregate =========
// wave per dst node; lane = h*16 + c. Emits g2s = fe @ W2fij as well.
__global__ __launch_bounds__(256, 4) void k_l1(
    const int* __restrict__ offs, const int* __restrict__ srcs,
    const int* __restrict__ eid, const float* __restrict__ ef,
    const _Float16* __restrict__ nf16, const float* __restrict__ fni,
    const float* __restrict__ fnj, const float* __restrict__ Wfij,
    const float* __restrict__ bedge, const float* __restrict__ attn,
    const float* __restrict__ Wfij2,
    float* __restrict__ g2s, _Float16* __restrict__ zbuf, int n)
{
    const int lane = threadIdx.x & 63;
    const int node = __builtin_amdgcn_readfirstlane(blockIdx.x * 4 + (threadIdx.x >> 6));
    if (node >= n) return;
    const int beg = offs[node], end = offs[node + 1];
    const float fjb = fnj[(size_t)node * 64 + lane] + bedge[lane];
    const float at = attn[lane];
    const float w2f = Wfij2[(lane & 15) * 4 + (lane >> 4)];
    float wf[32];
#pragma unroll
    for (int k = 0; k < 32; k++) wf[k] = Wfij[k * 64 + lane];
    // Force wf into registers: opaque touch makes re-loading unsound.
#pragma unroll
    for (int k = 0; k < 32; k++) asm volatile("" : "+v"(wf[k]));

    float s0 = 0.f, s1 = 0.f, s2 = 0.f, s3 = 0.f;
    vf2 z0 = {0.f, 0.f}, z1 = {0.f, 0.f}, z2 = {0.f, 0.f}, z3 = {0.f, 0.f};

    for (int base = beg; base < end; base += 64) {
        const int rem = end - base;
        const int cnt = (rem < 64) ? rem : 64;
        const int idx = base + ((lane < cnt) ? lane : (cnt - 1));
        const int spv = srcs[idx];
        const int edv = eid[idx];
#pragma unroll 2
        for (int it = 0; it < cnt; ++it) {
            const int sp = __builtin_amdgcn_readlane(spv, it);
            const int ed = __builtin_amdgcn_readlane(edv, it);
            // wave-uniform ef row: value identical across lanes
            const vf4* __restrict__ efr =
                (const vf4*)(ef + ((size_t)(unsigned)ed << 5));
            const vf4 q0 = __builtin_nontemporal_load(efr + 0);
            const vf4 q1 = __builtin_nontemporal_load(efr + 1);
            const vf4 q2 = __builtin_nontemporal_load(efr + 2);
            const vf4 q3 = __builtin_nontemporal_load(efr + 3);
            const vf4 q4 = __builtin_nontemporal_load(efr + 4);
            const vf4 q5 = __builtin_nontemporal_load(efr + 5);
            const vf4 q6 = __builtin_nontemporal_load(efr + 6);
            const vf4 q7 = __builtin_nontemporal_load(efr + 7);
            // 4 independent partial chains (dep depth 8 instead of 32)
            float f0 = fni[(size_t)(unsigned)sp * 64 + lane] + fjb;
            f0 = fmaf(q0.x, wf[0],  f0); f0 = fmaf(q0.y, wf[1],  f0);
            f0 = fmaf(q0.z, wf[2],  f0); f0 = fmaf(q0.w, wf[3],  f0);
            f0 = fmaf(q1.x, wf[4],  f0); f0 = fmaf(q1.y, wf[5],  f0);
            f0 = fmaf(q1.z, wf[6],  f0); f0 = fmaf(q1.w, wf[7],  f0);
            float f1 = q2.x * wf[8];
            f1 = fmaf(q2.y, wf[9],  f1); f1 = fmaf(q2.z, wf[10], f1);
            f1 = fmaf(q2.w, wf[11], f1); f1 = fmaf(q3.x, wf[12], f1);
            f1 = fmaf(q3.y, wf[13], f1); f1 = fmaf(q3.z, wf[14], f1);
            f1 = fmaf(q3.w, wf[15], f1);
            float f2 = q4.x * wf[16];
            f2 = fmaf(q4.y, wf[17], f2); f2 = fmaf(q4.z, wf[18], f2);
            f2 = fmaf(q4.w, wf[19], f2); f2 = fmaf(q5.x, wf[20], f2);
            f2 = fmaf(q5.y, wf[21], f2); f2 = fmaf(q5.z, wf[22], f2);
            f2 = fmaf(q5.w, wf[23], f2);
            float f3 = q6.x * wf[24];
            f3 = fmaf(q6.y, wf[25], f3); f3 = fmaf(q6.z, wf[26], f3);
            f3 = fmaf(q6.w, wf[27], f3); f3 = fmaf(q7.x, wf[28], f3);
            f3 = fmaf(q7.y, wf[29], f3); f3 = fmaf(q7.z, wf[30], f3);
            f3 = fmaf(q7.w, wf[31], f3);
            const float f = (f0 + f1) + (f2 + f3);
            const float fl = (f > 0.f) ? f : SLOPE * f;
            // relu-head-mean: every lane holds 4*fe[c], c=lane&15
            float r = fmaxf(fl, 0.f);
            r += __shfl_xor(r, 16, 64);
            r += __shfl_xor(r, 32, 64);
            // g2[h] = sum_c fe[c]*W2fij[c][h] -> lane 15 of each row
            float g = dpp_sum16(0.25f * r * w2f);
            if ((lane & 15) == 15)
                g2s[(size_t)(base + it) * 4 + (lane >> 4)] = g;
            // attention logits -> exp (logits are small; no max subtraction)
            const float t = dpp_sum16(fl * at);
            const float ce = __expf(t);
            const float c0 = bcast_lane(ce, 15);
            const float c1 = bcast_lane(ce, 31);
            const float c2 = bcast_lane(ce, 47);
            const float c3 = bcast_lane(ce, 63);
            // source node raw features (fp16): channels (2*lane, 2*lane+1)
            const vh2 nvh = *(const vh2*)(nf16 + (size_t)(unsigned)sp * 128 + lane * 2);
            const float nvx = (float)nvh.x, nvy = (float)nvh.y;
            s0 += c0; s1 += c1; s2 += c2; s3 += c3;
            z0.x = fmaf(c0, nvx, z0.x); z0.y = fmaf(c0, nvy, z0.y);
            z1.x = fmaf(c1, nvx, z1.x); z1.y = fmaf(c1, nvy, z1.y);
            z2.x = fmaf(c2, nvx, z2.x); z2.y = fmaf(c2, nvy, z2.y);
            z3.x = fmaf(c3, nvx, z3.x); z3.y = fmaf(c3, nvy, z3.y);
        }
    }
    const float i0 = (s0 > 0.f) ? 1.f / s0 : 0.f;
    const float i1 = (s1 > 0.f) ? 1.f / s1 : 0.f;
    const float i2 = (s2 > 0.f) ? 1.f / s2 : 0.f;
    const float i3 = (s3 > 0.f) ? 1.f / s3 : 0.f;
    // zbuf (fp16) layout: [node][h*128 + channel], channel = 2*lane (+1)
    _Float16* zb = zbuf + (size_t)node * 512;
    vh2 o;
    o.x = (_Float16)(z0.x * i0); o.y = (_Float16)(z0.y * i0);
    *(vh2*)(zb + 0   + lane * 2) = o;
    o.x = (_Float16)(z1.x * i1); o.y = (_Float16)(z1.y * i1);
    *(vh2*)(zb + 128 + lane * 2) = o;
    o.x = (_Float16)(z2.x * i2); o.y = (_Float16)(z2.y * i2);
    *(vh2*)(zb + 256 + lane * 2) = o;
    o.x = (_Float16)(z3.x * i3); o.y = (_Float16)(z3.y * i3);
    *(vh2*)(zb + 384 + lane * 2) = o;
}

// ====== z-space -> hbuf projection: hbuf = 0.25*sum_h relu(z_h@Wnode_h + b_h)
__global__ __launch_bounds__(256) void k_zproj(
    const _Float16* __restrict__ zbuf, const int* __restrict__ offs,
    const float* __restrict__ Wnode, const float* __restrict__ bnode,
    float* __restrict__ hbuf, int n)
{
    __shared__ float s[512][20];
    const int t = threadIdx.x;
    const int node0 = blockIdx.x * NPB;
    for (int i = 0; i < 16; i++) {
        const int idx = i * 256 + t;          // 0..4095 (vh2 pairs)
        const int nl = idx >> 8, kk = (idx & 255) * 2;
        const int node = node0 + nl;
        vh2 v = {0.f, 0.f};
        if (node < n) v = *(const vh2*)(zbuf + (size_t)node * 512 + kk);
        s[kk][nl]     = (float)v.x;
        s[kk + 1][nl] = (float)v.y;
    }
    __syncthreads();
    const int lane = t & 63;
    const int w4 = (t >> 6) * 4;
    bool zf[4];
    float hb[4] = {0, 0, 0, 0};
#pragma unroll
    for (int nn = 0; nn < 4; nn++) {
        const int node = node0 + w4 + nn;
        zf[nn] = (node < n) && (offs[node] < offs[node + 1]);
    }
#pragma unroll
    for (int h = 0; h < 4; h++) {
        float acc[4];
        const float bv = bnode[h * 64 + lane];
#pragma unroll
        for (int nn = 0; nn < 4; nn++) acc[nn] = zf[nn] ? bv : 0.f;
#pragma unroll 4
        for (int k = 0; k < 128; k++) {
            const float wv = Wnode[(size_t)k * 256 + h * 64 + lane];
            const float4 sv = *(const float4*)&s[h * 128 + k][w4];
            acc[0] = fmaf(wv, sv.x, acc[0]);
            acc[1] = fmaf(wv, sv.y, acc[1]);
            acc[2] = fmaf(wv, sv.z, acc[2]);
            acc[3] = fmaf(wv, sv.w, acc[3]);
        }
#pragma unroll
        for (int nn = 0; nn < 4; nn++) hb[nn] += fmaxf(acc[nn], 0.f);
    }
#pragma unroll
    for (int nn = 0; nn < 4; nn++) {
        const int node = node0 + w4 + nn;
        if (node < n) hbuf[(size_t)node * 64 + lane] = 0.25f * hb[nn];
    }
}

// ======================= layer-2 node projections ===========================
__global__ __launch_bounds__(256) void k_nodeproj2(
    const float* __restrict__ hbuf, const float* __restrict__ Wni,
    const float* __restrict__ Wnj, const float* __restrict__ Wnode,
    const float* __restrict__ bnode,
    float* __restrict__ fni2, float* __restrict__ fnj2,
    _Float16* __restrict__ ft2h, int n)
{
    __shared__ float sh[4][64];
    const int lane = threadIdx.x & 63, w = threadIdx.x >> 6;
    const int node = blockIdx.x * 4 + w;
    const int nc = (node < n) ? node : (n - 1);
    const float v = hbuf[(size_t)nc * 64 + lane];
    sh[w][lane] = v;
    __syncthreads();
    float acc = bnode[lane];
#pragma unroll 4
    for (int k = 0; k < 64; k++) acc = fmaf(sh[w][k], Wnode[k * 64 + lane], acc);
    float pi[4], pj[4];
#pragma unroll
    for (int h = 0; h < 4; h++) { pi[h] = v * Wni[lane * 4 + h]; pj[h] = v * Wnj[lane * 4 + h]; }
#pragma unroll
    for (int mk = 1; mk < 64; mk <<= 1) {
#pragma unroll
        for (int h = 0; h < 4; h++) {
            pi[h] += __shfl_xor(pi[h], mk, 64);
            pj[h] += __shfl_xor(pj[h], mk, 64);
        }
    }
    if (node < n) {
        ft2h[(size_t)node * 64 + lane] = (_Float16)acc;
        if (lane == 0) {
            *(float4*)(fni2 + (size_t)node * 4) = make_float4(pi[0], pi[1], pi[2], pi[3]);
            *(float4*)(fnj2 + (size_t)node * 4) = make_float4(pj[0], pj[1], pj[2], pj[3]);
        }
    }
}

// ====== layer-2 fused: edge logits + softmax + message passing ==============
// wave per dst node; lane = h*16 + class.
__global__ __launch_bounds__(256) void k_l2(
    const int* __restrict__ offs, const int* __restrict__ srcs,
    const float* __restrict__ g2s, const float* __restrict__ fni2,
    const float* __restrict__ fnj2, const _Float16* __restrict__ ft2h,
    const float* __restrict__ bedge2, const float* __restrict__ attn2,
    float* __restrict__ out, int n)
{
    const int lane = threadIdx.x & 63;
    const int node = __builtin_amdgcn_readfirstlane(blockIdx.x * 4 + (threadIdx.x >> 6));
    if (node >= n) return;
    const int beg = offs[node], end = offs[node + 1];
    const int h = lane >> 4;
    const float base_ = fnj2[(size_t)node * 4 + h] + bedge2[h];
    const float at = attn2[h];
    float s = 0.f, acc = 0.f;
    for (int base = beg; base < end; base += 64) {
        const int rem = end - base;
        const int cnt = (rem < 64) ? rem : 64;
        const int idx = base + ((lane < cnt) ? lane : (cnt - 1));
        const int spv = srcs[idx];
#pragma unroll 2
        for (int it = 0; it < cnt; ++it) {
            const int sp = __builtin_amdgcn_readlane(spv, it);
            const int p = base + it;
            const vf4 gq = *(const vf4*)(g2s + (size_t)p * 4);
            const float4 fq = *(const float4*)(fni2 + (size_t)(unsigned)sp * 4);
            const float gh = (h == 0) ? gq.x : (h == 1) ? gq.y : (h == 2) ? gq.z : gq.w;
            const float fh = (h == 0) ? fq.x : (h == 1) ? fq.y : (h == 2) ? fq.z : fq.w;
            const float f = base_ + fh + gh;
            const float fl = (f > 0.f) ? f : SLOPE * f;
            const float c = __expf(fl * at);
            s += c;
            const float ftv = (float)ft2h[(size_t)(unsigned)sp * 64 + lane];
            acc = fmaf(c, ftv, acc);
        }
    }
    out[(size_t)node * 64 + lane] = (s > 0.f) ? acc / s : 0.f;
}

extern "C" void kernel_launch(void* const* d_in, const int* in_sizes, int n_in,
                              void* d_out, int out_size, void* d_ws, size_t ws_size,
                              hipStream_t stream)
{
    const float* nfeat  = (const float*)d_in[0];
    const float* efeat  = (const float*)d_in[1];
    const int*   src    = (const int*)d_in[2];
    const int*   dst    = (const int*)d_in[3];
    const float* W1ni   = (const float*)d_in[4];
    const float* W1fij  = (const float*)d_in[5];
    const float* W1nj   = (const float*)d_in[6];
    const float* b1e    = (const float*)d_in[7];
    const float* W1node = (const float*)d_in[8];
    const float* b1n    = (const float*)d_in[9];
    const float* attn1  = (const float*)d_in[10];
    const float* W2ni   = (const float*)d_in[11];
    const float* W2fij  = (const float*)d_in[12];
    const float* W2nj   = (const float*)d_in[13];
    const float* b2e    = (const float*)d_in[14];
    const float* W2node = (const float*)d_in[15];
    const float* b2n    = (const float*)d_in[16];
    const float* attn2  = (const float*)d_in[17];
    const int n = in_sizes[0] / 128;
    const int E = in_sizes[2];
    float* out = (float*)d_out;

    char* w = (char*)d_ws;
    auto alloc = [&](size_t bytes) {
        char* p = w; w += (bytes + 255) & ~(size_t)255; return p;
    };
    _Float16* zbuf = (_Float16*)alloc((size_t)n * 512 * 2);  // reused for ft2h
    float*    g2s  = (float*)alloc((size_t)E * 4 * 4);
    float*    fni  = (float*)alloc((size_t)n * 64 * 4);      // reused as hbuf
    float*    fnj  = (float*)alloc((size_t)n * 64 * 4);
    _Float16* nf16 = (_Float16*)alloc((size_t)n * 128 * 2);
    int*      deg  = (int*)alloc((size_t)n * 4);
    int*      offs = (int*)alloc((size_t)(n + 1) * 4);
    int*      curs = (int*)alloc((size_t)n * 4);
    int*      srcs = (int*)alloc((size_t)E * 4);
    int*      eid  = (int*)alloc((size_t)E * 4);
    float*    fni2 = (float*)alloc((size_t)n * 4 * 4);
    float*    fnj2 = (float*)alloc((size_t)n * 4 * 4);
    float*    hbuf = fni;                 // fni dead after k_l1
    _Float16* ft2h = zbuf;                // zbuf dead after k_zproj

    // ---- CSR build
    hipMemsetAsync(deg, 0, (size_t)n * 4, stream);
    k_deg<<<(E + 255) / 256, 256, 0, stream>>>(dst, deg, E);
    k_scan<<<1, 1024, 0, stream>>>(deg, offs, curs, n);
    k_scatter<<<(E + 255) / 256, 256, 0, stream>>>(src, dst, curs, srcs, eid, E);

    // ---- layer 1
    k_nodeproj1<<<(n + NPB - 1) / NPB, 256, 0, stream>>>(
        nfeat, W1ni, W1nj, fni, fnj, nf16, n);
    k_l1<<<(n + 3) / 4, 256, 0, stream>>>(offs, srcs, eid, efeat, nf16,
                                          fni, fnj, W1fij, b1e, attn1, W2fij,
                                          g2s, zbuf, n);
    k_zproj<<<(n + NPB - 1) / NPB, 256, 0, stream>>>(zbuf, offs, W1node, b1n,
                                                     hbuf, n);
    // ---- layer 2
    k_nodeproj2<<<(n + 3) / 4, 256, 0, stream>>>(hbuf, W2ni, W2nj, W2node, b2n,
                                                 fni2, fnj2, ft2h, n);
    k_l2<<<(n + 3) / 4, 256, 0, stream>>>(offs, srcs, g2s, fni2, fnj2, ft2h,
                                          b2e, attn2, out, n);
}